// Round 11
// baseline (354.195 us; speedup 1.0000x reference)
//
#include <hip/hip_runtime.h>
#include <hip/hip_cooperative_groups.h>
#include <hip/hip_bf16.h>
#include <math.h>

namespace cg = cooperative_groups;

#define TOK 4096
#define CDIM 512
#define NHEADS 8
#define DH 64
#define NBH 16
#define NSEQ 2048
#define SQRT_C 22.62741699796952f
#define ATTN_SCALE 0.125f

typedef unsigned short ushort_t;
typedef __attribute__((ext_vector_type(8))) short short8;
typedef __attribute__((ext_vector_type(4))) short short4v;
typedef __attribute__((ext_vector_type(16))) float f32x16;
typedef __attribute__((ext_vector_type(4))) float f32x4;

__device__ inline ushort_t f2b(float f) {
  __hip_bfloat16 h = __float2bfloat16(f);
  return *(ushort_t*)&h;
}
__device__ inline f32x16 fzero16() {
  f32x16 v;
#pragma unroll
  for (int i = 0; i < 16; ++i) v[i] = 0.0f;
  return v;
}
__device__ inline void gload16(const ushort_t* g, ushort_t* l) {
  __builtin_amdgcn_global_load_lds(
      (const __attribute__((address_space(1))) unsigned int*)g,
      (__attribute__((address_space(3))) unsigned int*)l, 16, 0, 0);
}

// ===========================================================================
// Shared device bodies (used by both the mega kernel and the fallback path)
// ===========================================================================

// ---- prep: one wave handles one 512-float row ----
__device__ __forceinline__ void prep_row(
    const float* __restrict__ src, ushort_t* __restrict__ dst,
    float* __restrict__ xs, int row, int lane, bool isx) {
  const float4* p = (const float4*)(src + (size_t)row * CDIM);
  float4 a = p[lane];
  float4 b = p[lane + 64];
  float s = a.x * a.x + a.y * a.y + a.z * a.z + a.w * a.w
          + b.x * b.x + b.y * b.y + b.z * b.z + b.w * b.w;
#pragma unroll
  for (int off = 32; off > 0; off >>= 1) s += __shfl_down(s, off);
  s = __shfl(s, 0);
  float inv;
  if (isx) {
    if (lane == 0) xs[row] = 1.0f / (sqrtf(s) * SQRT_C);
    inv = 1.0f;
  } else {
    inv = 1.0f / sqrtf(s);
  }
  short4v ya, yb;
  ya[0] = (short)f2b(a.x * inv); ya[1] = (short)f2b(a.y * inv);
  ya[2] = (short)f2b(a.z * inv); ya[3] = (short)f2b(a.w * inv);
  yb[0] = (short)f2b(b.x * inv); yb[1] = (short)f2b(b.y * inv);
  yb[2] = (short)f2b(b.z * inv); yb[3] = (short)f2b(b.w * inv);
  *(short4v*)&dst[(size_t)row * CDIM + lane * 4] = ya;
  *(short4v*)&dst[(size_t)row * CDIM + 256 + lane * 4] = yb;
}

// ---- bcos GEMM 128m x 64ch tile, BK=64 as two BK=32 sub-stages ----
// MODE 0: Qb [bh][n][64] (x0.125), Kt/Vt [bh][d][n] via LDS transpose.
// MODE 1: fp32 out; osum_p[8][4096] summed into osl, rsqrt in epilogue.
template <int MODE>
__device__ __forceinline__ void gemm_tile_body(
    const ushort_t* __restrict__ Ab, const ushort_t* __restrict__ Wn,
    const float* __restrict__ ascale, const float* __restrict__ osum_p,
    float* __restrict__ out,
    ushort_t* __restrict__ Qb, ushort_t* __restrict__ Ktb,
    ushort_t* __restrict__ Vtb,
    int P, int n0, int mb, ushort_t* pool, float* osl, int t) {
  const int lane = t & 63;
  const int w = t >> 6;
  const int mq = w & 1, wq = w >> 1;
  const int l15 = lane & 15, l4 = lane >> 4;

  if (MODE == 1) {
    if (t < 128) {
      float s = 0.f;
#pragma unroll
      for (int hh = 0; hh < 8; ++hh) s += osum_p[hh * TOK + mb + t];
      osl[t] = s;
    }
  }

  const int srow = lane >> 2;
  const int sch = (lane & 3) * 8;
  const ushort_t* ag[2];
  const ushort_t* wg[2];
  ushort_t* al[2];
  ushort_t* wl[2];
#pragma unroll
  for (int i = 0; i < 2; ++i) {
    int r = w * 32 + i * 16;
    ag[i] = Ab + (size_t)(mb + r + srow) * CDIM + sch;
    al[i] = pool + r * 32;
    int g = r >> 4;
    int grow = n0 + (g >> 1) * 16 + srow + (g & 1) * P;
    wg[i] = Wn + (size_t)grow * CDIM + sch;
    wl[i] = pool + 8192 + r * 32;
  }

  f32x4 acc[4][4];
#pragma unroll
  for (int i = 0; i < 4; ++i)
#pragma unroll
    for (int j = 0; j < 4; ++j) acc[i][j] = (f32x4){0.f, 0.f, 0.f, 0.f};

  for (int it = 0; it < 8; ++it) {
    __syncthreads();
#pragma unroll
    for (int h = 0; h < 2; ++h)
#pragma unroll
      for (int i = 0; i < 2; ++i) {
        gload16(ag[i] + h * 32, al[i] + h * 4096);
        gload16(wg[i] + h * 32, wl[i] + h * 4096);
      }
#pragma unroll
    for (int i = 0; i < 2; ++i) { ag[i] += 64; wg[i] += 64; }
    __syncthreads();
#pragma unroll
    for (int h = 0; h < 2; ++h) {
      short8 af[4], wf[4];
#pragma unroll
      for (int i = 0; i < 4; ++i)
        af[i] = *(const short8*)(pool + h * 4096 + (mq * 64 + i * 16 + l15) * 32 + l4 * 8);
#pragma unroll
      for (int j = 0; j < 4; ++j)
        wf[j] = *(const short8*)(pool + 8192 + h * 4096 + (wq * 64 + j * 16 + l15) * 32 + l4 * 8);
#pragma unroll
      for (int i = 0; i < 4; ++i)
#pragma unroll
        for (int j = 0; j < 4; ++j)
          acc[i][j] = __builtin_amdgcn_mfma_f32_16x16x32_bf16(af[i], wf[j], acc[i][j], 0, 0, 0);
    }
  }

  if (MODE == 0) {
    const int which = n0 >> 9;
    const int h = (n0 & 511) >> 6;
    const int b = mb >> 11;
    const int bh = b * NHEADS + h;
    const int nsb = mb & 2047;
    __syncthreads();
    if (which == 0) {
      // Q: LDS [n 128][dh 64] pad 72
#pragma unroll
      for (int i = 0; i < 4; ++i) {
        const int ml = mq * 64 + i * 16 + l4 * 4;
        const float4 asc = *(const float4*)&ascale[mb + ml];
        const float ascv[4] = {asc.x, asc.y, asc.z, asc.w};
#pragma unroll
        for (int jt = 0; jt < 2; ++jt) {
          const int dh = (wq * 2 + jt) * 16 + l15;
          f32x4 a0 = acc[i][2 * jt], a1 = acc[i][2 * jt + 1];
#pragma unroll
          for (int r = 0; r < 4; ++r) {
            float v = fmaxf(a0[r], a1[r]);
            pool[(ml + r) * 72 + dh] = f2b(v * fabsf(v) * ascv[r] * ATTN_SCALE);
          }
        }
      }
      __syncthreads();
      ushort_t* gq = Qb + ((size_t)bh * NSEQ + nsb) * DH;
#pragma unroll
      for (int p = 0; p < 4; ++p) {
        int idx = p * 256 + t;
        int row = idx >> 3, c8 = idx & 7;
        *(short8*)(gq + row * DH + c8 * 8) = *(const short8*)(pool + row * 72 + c8 * 8);
      }
    } else {
      // K/V: LDS [dh 64][n 128] pad 136
#pragma unroll
      for (int i = 0; i < 4; ++i) {
        const int ml = mq * 64 + i * 16 + l4 * 4;
        const float4 asc = *(const float4*)&ascale[mb + ml];
        const float ascv[4] = {asc.x, asc.y, asc.z, asc.w};
#pragma unroll
        for (int jt = 0; jt < 2; ++jt) {
          const int dh = (wq * 2 + jt) * 16 + l15;
          f32x4 a0 = acc[i][2 * jt], a1 = acc[i][2 * jt + 1];
          short4v pv;
#pragma unroll
          for (int r = 0; r < 4; ++r) {
            float v = fmaxf(a0[r], a1[r]);
            pv[r] = (short)f2b(v * fabsf(v) * ascv[r]);
          }
          *(short4v*)(pool + dh * 136 + ml) = pv;
        }
      }
      __syncthreads();
      ushort_t* gk = ((which == 1) ? Ktb : Vtb) + (size_t)bh * DH * NSEQ + nsb;
#pragma unroll
      for (int p = 0; p < 4; ++p) {
        int idx = p * 256 + t;
        int dh_r = idx >> 4, ch = idx & 15;
        *(short8*)(gk + (size_t)dh_r * NSEQ + ch * 8) =
            *(const short8*)(pool + dh_r * 136 + ch * 8);
      }
    }
  } else {
#pragma unroll
    for (int i = 0; i < 4; ++i) {
      const int ml = mq * 64 + i * 16 + l4 * 4;
      const int m = mb + ml;
      float ascv[4];
#pragma unroll
      for (int r = 0; r < 4; ++r) ascv[r] = 1.0f / (sqrtf(osl[ml + r]) * SQRT_C);
#pragma unroll
      for (int jt = 0; jt < 2; ++jt) {
        const int c = n0 + (wq * 2 + jt) * 16 + l15;
        f32x4 a0 = acc[i][2 * jt], a1 = acc[i][2 * jt + 1];
#pragma unroll
        for (int r = 0; r < 4; ++r) {
          float v = fmaxf(a0[r], a1[r]);
          out[(size_t)(m + r) * CDIM + c] = v * fabsf(v) * ascv[r];
        }
      }
    }
  }
}

// ---- kvstat: one 256-key slice of one bh -> partial stats (no atomics) ----
__device__ __forceinline__ void kvstat_body(
    const ushort_t* __restrict__ Ktb, const ushort_t* __restrict__ Vtb,
    float* __restrict__ Agp, float* Lr, int sl, int bh, int t) {
  const int lane = t & 63;
  const int w = t >> 6;
  const int l31 = lane & 31;
  const int H = lane >> 5;
  const int n0 = sl * 256 + w * 64;

  short8 onesf;
  {
    short v = (l31 == 0) ? (short)0x3F80 : (short)0;
#pragma unroll
    for (int i = 0; i < 8; ++i) onesf[i] = v;
  }

  f32x16 acc[3][3];
#pragma unroll
  for (int mt = 0; mt < 3; ++mt)
#pragma unroll
    for (int nt = 0; nt < 3; ++nt) acc[mt][nt] = fzero16();

  const ushort_t* Kbase = Ktb + (size_t)bh * DH * NSEQ;
  const ushort_t* Vbase = Vtb + (size_t)bh * DH * NSEQ;
#pragma unroll
  for (int c = 0; c < 4; ++c) {
    const int key = n0 + c * 16 + H * 8;
    short8 kf[2], vf[2];
#pragma unroll
    for (int mt = 0; mt < 2; ++mt) {
      kf[mt] = *(const short8*)(Kbase + (size_t)(mt * 32 + l31) * NSEQ + key);
      vf[mt] = *(const short8*)(Vbase + (size_t)(mt * 32 + l31) * NSEQ + key);
    }
#pragma unroll
    for (int mt = 0; mt < 3; ++mt) {
      short8 a = (mt < 2) ? kf[mt] : onesf;
#pragma unroll
      for (int nt = 0; nt < 3; ++nt) {
        if (mt == 2 && nt == 2) continue;
        short8 bfr = (nt < 2) ? vf[nt] : onesf;
        acc[mt][nt] = __builtin_amdgcn_mfma_f32_32x32x16_bf16(a, bfr, acc[mt][nt], 0, 0, 0);
      }
    }
  }

  float* D = Lr + (w & 1) * (66 * 66);
  if (w < 2) {
#pragma unroll
    for (int mt = 0; mt < 3; ++mt)
#pragma unroll
      for (int nt = 0; nt < 3; ++nt) {
        if (mt == 2 && nt == 2) continue;
#pragma unroll
        for (int r = 0; r < 16; ++r) {
          int rloc = (r & 3) + 8 * (r >> 2) + 4 * H;
          int row = (mt < 2) ? mt * 32 + rloc : 64;
          int col = (nt < 2) ? nt * 32 + l31 : 64;
          bool valid = (mt < 2 || rloc == 0) && (nt < 2 || l31 == 0);
          if (valid) D[row * 66 + col] = acc[mt][nt][r];
        }
      }
  }
  __syncthreads();
  if (w >= 2) {
#pragma unroll
    for (int mt = 0; mt < 3; ++mt)
#pragma unroll
      for (int nt = 0; nt < 3; ++nt) {
        if (mt == 2 && nt == 2) continue;
#pragma unroll
        for (int r = 0; r < 16; ++r) {
          int rloc = (r & 3) + 8 * (r >> 2) + 4 * H;
          int row = (mt < 2) ? mt * 32 + rloc : 64;
          int col = (nt < 2) ? nt * 32 + l31 : 64;
          bool valid = (mt < 2 || rloc == 0) && (nt < 2 || l31 == 0);
          if (valid) D[row * 66 + col] += acc[mt][nt][r];
        }
      }
  }
  __syncthreads();

  float* ag = Agp + ((size_t)sl * NBH + bh) * (66 * 64);
  const float* L0 = Lr;
  const float* L1 = Lr + 66 * 66;
  for (int e = t; e < 66 * 64; e += 256) {
    int j = e >> 6, i = e & 63;
    int idx = (j < 64) ? i * 66 + j : (j == 64 ? i * 66 + 64 : 64 * 66 + i);
    ag[e] = L0[idx] + L1[idx];
  }
}

// ---- attn_apply: 128-token block of one bh ----
__device__ __forceinline__ void attn_body(
    const ushort_t* __restrict__ Qb, const float* __restrict__ Agp,
    ushort_t* __restrict__ attnb, float* __restrict__ osum_p,
    ushort_t* Bs, float* vs_lds, int tokblk, int bh, int t) {
  const int lane = t & 63;
  const int w = t >> 6;
  const int l31 = lane & 31;
  const int H = lane >> 5;
  const int tok0 = tokblk * 128 + w * 32;

  const float* agp = Agp + (size_t)bh * (66 * 64);
  const size_t sstr = (size_t)NBH * 66 * 64;
  for (int e = t; e < 64 * 64; e += 256) {
    float s = 0.f;
#pragma unroll
    for (int sl = 0; sl < 8; ++sl) s += agp[sl * sstr + e];
    Bs[(e >> 6) * 72 + (e & 63)] = f2b(s);
  }
  for (int e = t; e < 32 * 64; e += 256) {
    int j = e >> 6, i = e & 63;
    ushort_t v = 0;
    if (j == 0) {
      float s = 0.f;
#pragma unroll
      for (int sl = 0; sl < 8; ++sl) s += agp[sl * sstr + 64 * 64 + i];
      v = f2b(s);
    }
    Bs[(64 + j) * 72 + i] = v;
  }
  if (t < 64) {
    float s = 0.f;
#pragma unroll
    for (int sl = 0; sl < 8; ++sl) s += agp[sl * sstr + 65 * 64 + t];
    vs_lds[t] = s;
  }
  __syncthreads();

  short8 qf[4];
  {
    const ushort_t* qp = Qb + ((size_t)bh * NSEQ + tok0 + l31) * DH + H * 8;
#pragma unroll
    for (int c = 0; c < 4; ++c) qf[c] = *(const short8*)(qp + c * 16);
  }

  f32x16 oacc[3];
#pragma unroll
  for (int nt = 0; nt < 3; ++nt) oacc[nt] = fzero16();
#pragma unroll
  for (int c = 0; c < 4; ++c) {
#pragma unroll
    for (int nt = 0; nt < 3; ++nt) {
      short8 bfr = *(const short8*)(Bs + (nt * 32 + l31) * 72 + c * 16 + H * 8);
      oacc[nt] = __builtin_amdgcn_mfma_f32_32x32x16_bf16(qf[c], bfr, oacc[nt], 0, 0, 0);
    }
  }

  const int b = bh >> 3, h = bh & 7;
#pragma unroll
  for (int r = 0; r < 16; ++r) {
    int rloc = (r & 3) + 8 * (r >> 2) + 4 * H;
    float den = 2048.0f + __shfl(oacc[2][r], H * 32);
    float inv = 1.0f / den;
    float v0 = (vs_lds[l31] + oacc[0][r]) * inv;
    float v1 = (vs_lds[32 + l31] + oacc[1][r]) * inv;
    int n = tok0 + rloc;
    ushort_t* op = attnb + ((size_t)(b * NSEQ + n)) * CDIM + h * DH;
    op[l31] = f2b(v0);
    op[32 + l31] = f2b(v1);
    float ss = v0 * v0 + v1 * v1;
#pragma unroll
    for (int off = 16; off > 0; off >>= 1) ss += __shfl_down(ss, off, 32);
    if (l31 == 0) osum_p[h * TOK + b * NSEQ + n] = ss;
  }
}

// ===========================================================================
// Mega kernel: all 5 phases with grid.sync(). 512 blocks x 256 threads.
// ===========================================================================
#define SMEM_BYTES 34848   // max(gemm 32768+512, kvstat 2*66*66*4, attn 14080)

__global__ __launch_bounds__(256, 2) void mega_kernel(
    const float* __restrict__ x, const float* __restrict__ W_qkv,
    const float* __restrict__ W_proj, float* __restrict__ out,
    ushort_t* __restrict__ Wqn, ushort_t* __restrict__ Wpn,
    ushort_t* __restrict__ xb, ushort_t* __restrict__ Qb,
    ushort_t* __restrict__ Ktb, ushort_t* __restrict__ Vtb,
    float* __restrict__ xs, float* __restrict__ osum_p,
    float* __restrict__ Agp) {
  __shared__ __align__(16) unsigned char smem[SMEM_BYTES];
  cg::grid_group grid = cg::this_grid();
  const int t = threadIdx.x;
  const int tb = blockIdx.x;
  const int lane = t & 63;
  const int w = t >> 6;

  // Phase A: prep — 8192 rows over 2048 waves (4 rows/wave)
  {
    int gwave = tb * 4 + w;
    for (int row = gwave; row < 8192; row += 2048) {
      if (row < 3072)      prep_row(W_qkv, Wqn, xs, row, lane, false);
      else if (row < 4096) prep_row(W_proj, Wpn + (size_t)(row - 3072) * CDIM - (size_t)(row - 3072) * CDIM, xs, row - 3072, lane, false),
                           (void)0;
      else                 prep_row(x, xb, xs, row - 4096, lane, true);
    }
  }
  grid.sync();

  // Phase B: gemm0 K/V tiles — 512 tiles (ct 8..23, mt 0..31), 1 per block
  {
    ushort_t* pool = (ushort_t*)smem;
    float* osl = (float*)(smem + 32768);
    int ct = 8 + (tb & 15), mt = tb >> 4;
    gemm_tile_body<0>(xb, Wqn, xs, nullptr, nullptr, Qb, Ktb, Vtb,
                      1536, ct * 64, mt * 128, pool, osl, t);
  }
  grid.sync();

  // Phase C: gemm0 Q tiles (blocks 0..255) + kvstat (blocks 256..383)
  if (tb < 256) {
    ushort_t* pool = (ushort_t*)smem;
    float* osl = (float*)(smem + 32768);
    int ct = tb & 7, mt = tb >> 3;
    gemm_tile_body<0>(xb, Wqn, xs, nullptr, nullptr, Qb, Ktb, Vtb,
                      1536, ct * 64, mt * 128, pool, osl, t);
  } else if (tb < 384) {
    int idx = tb - 256;
    kvstat_body(Ktb, Vtb, Agp, (float*)smem, idx >> 4, idx & 15, t);
  }
  grid.sync();

  // Phase D: attn_apply — 256 units (blocks 0..255); attnb overlays xb
  if (tb < 256) {
    attn_body(Qb, Agp, xb, osum_p, (ushort_t*)smem, (float*)(smem + 13824),
              tb >> 4, tb & 15, t);
  }
  grid.sync();

  // Phase E: gemm1 — 256 tiles (ct 0..7, mt 0..31)
  if (tb < 256) {
    ushort_t* pool = (ushort_t*)smem;
    float* osl = (float*)(smem + 32768);
    int ct = tb & 7, mt = tb >> 3;
    gemm_tile_body<1>(xb, Wpn, nullptr, osum_p, out, nullptr, nullptr, nullptr,
                      512, ct * 64, mt * 128, pool, osl, t);
  }
}

// ===========================================================================
// Fallback standalone kernels (R10 path) — used if cooperative launch fails
// ===========================================================================
__global__ __launch_bounds__(64) void prep_kernel(
    const float* __restrict__ W_qkv, const float* __restrict__ W_proj,
    const float* __restrict__ x,
    ushort_t* __restrict__ Wqn, ushort_t* __restrict__ Wpn,
    ushort_t* __restrict__ xb, float* __restrict__ xs) {
  const int bid = blockIdx.x;
  if (bid < 3072)      prep_row(W_qkv, Wqn, xs, bid, threadIdx.x, false);
  else if (bid < 4096) prep_row(W_proj, Wpn, xs, bid - 3072, threadIdx.x, false);
  else                 prep_row(x, xb, xs, bid - 4096, threadIdx.x, true);
}

template <int MODE>
__global__ __launch_bounds__(256) void gemm_mfma_kernel(
    const ushort_t* __restrict__ Ab, const ushort_t* __restrict__ Wn,
    const float* __restrict__ ascale, const float* __restrict__ osum_p,
    float* __restrict__ out,
    ushort_t* __restrict__ Qb, ushort_t* __restrict__ Ktb,
    ushort_t* __restrict__ Vtb, int P) {
  __shared__ __align__(16) ushort_t pool[16384];
  __shared__ float osl[128];
  gemm_tile_body<MODE>(Ab, Wn, ascale, osum_p, out, Qb, Ktb, Vtb, P,
                       blockIdx.x * 64, blockIdx.y * 128, pool, osl, threadIdx.x);
}

__global__ __launch_bounds__(256) void kvstat_kernel(
    const ushort_t* __restrict__ Ktb, const ushort_t* __restrict__ Vtb,
    float* __restrict__ Agp) {
  __shared__ float Lr[2 * 66 * 66];
  kvstat_body(Ktb, Vtb, Agp, Lr, blockIdx.x, blockIdx.y, threadIdx.x);
}

__global__ __launch_bounds__(256) void attn_apply_kernel(
    const ushort_t* __restrict__ Qb, const float* __restrict__ Agp,
    ushort_t* __restrict__ attnb, float* __restrict__ osum_p) {
  __shared__ __align__(16) ushort_t Bs[96 * 72];
  __shared__ float vs_lds[64];
  attn_body(Qb, Agp, attnb, osum_p, Bs, vs_lds, blockIdx.x, blockIdx.y, threadIdx.x);
}

// ===========================================================================
extern "C" void kernel_launch(void* const* d_in, const int* in_sizes, int n_in,
                              void* d_out, int out_size, void* d_ws, size_t ws_size,
                              hipStream_t stream) {
  const float* x      = (const float*)d_in[0];
  const float* W_qkv  = (const float*)d_in[1];
  const float* W_proj = (const float*)d_in[2];
  float* out = (float*)d_out;

  char* wsb = (char*)d_ws;
  ushort_t* Wqn = (ushort_t*)(wsb + 0);          // 3072x512 bf16
  ushort_t* Wpn = (ushort_t*)(wsb + 3145728);    // 1024x512 bf16
  ushort_t* xb  = (ushort_t*)(wsb + 4194304);    // 4096x512 bf16; reused as attnb
  ushort_t* Qb  = (ushort_t*)(wsb + 8388608);    // [bh][n][64] bf16
  ushort_t* Ktb = (ushort_t*)(wsb + 12582912);   // [bh][d][n] bf16
  ushort_t* Vtb = (ushort_t*)(wsb + 16777216);   // [bh][dh][n] bf16
  float* xs     = (float*)(wsb + 20971520);      // 4096
  float* osum_p = (float*)(wsb + 20987904);      // 8 x 4096
  float* Agp    = (float*)(wsb + 21118976);      // 8 x 16 x 66*64

  void* args[] = {(void*)&x, (void*)&W_qkv, (void*)&W_proj, (void*)&out,
                  (void*)&Wqn, (void*)&Wpn, (void*)&xb, (void*)&Qb,
                  (void*)&Ktb, (void*)&Vtb, (void*)&xs, (void*)&osum_p,
                  (void*)&Agp};
  hipError_t e = hipLaunchCooperativeKernel((const void*)mega_kernel,
                                            dim3(512), dim3(256), args, 0, stream);
  if (e != hipSuccess) {
    // Fallback: R10 5-dispatch path
    prep_kernel<<<8192, 64, 0, stream>>>(W_qkv, W_proj, x, Wqn, Wpn, xb, xs);
    gemm_mfma_kernel<0><<<dim3(24, 32), 256, 0, stream>>>(
        xb, Wqn, xs, nullptr, nullptr, Qb, Ktb, Vtb, 1536);
    kvstat_kernel<<<dim3(8, NBH), 256, 0, stream>>>(Ktb, Vtb, Agp);
    attn_apply_kernel<<<dim3(16, NBH), 256, 0, stream>>>(Qb, Agp, xb, osum_p);
    gemm_mfma_kernel<1><<<dim3(8, 32), 256, 0, stream>>>(
        xb, Wpn, nullptr, osum_p, out, nullptr, nullptr, nullptr, 512);
  }
}

// Round 12
// 122.144 us; speedup vs baseline: 2.8998x; 2.8998x over previous
//
#include <hip/hip_runtime.h>
#include <hip/hip_bf16.h>
#include <math.h>

#define TOK 4096
#define CDIM 512
#define NHEADS 8
#define DH 64
#define NBH 16
#define NSEQ 2048
#define SQRT_C 22.62741699796952f
#define ATTN_SCALE 0.125f

typedef unsigned short ushort_t;
typedef __attribute__((ext_vector_type(8))) short short8;
typedef __attribute__((ext_vector_type(4))) short short4v;
typedef __attribute__((ext_vector_type(16))) float f32x16;
typedef __attribute__((ext_vector_type(4))) float f32x4;

__device__ inline ushort_t f2b(float f) {
  __hip_bfloat16 h = __float2bfloat16(f);
  return *(ushort_t*)&h;
}
__device__ inline f32x16 fzero16() {
  f32x16 v;
#pragma unroll
  for (int i = 0; i < 16; ++i) v[i] = 0.0f;
  return v;
}
__device__ inline void gload16(const ushort_t* g, ushort_t* l) {
  __builtin_amdgcn_global_load_lds(
      (const __attribute__((address_space(1))) unsigned int*)g,
      (__attribute__((address_space(3))) unsigned int*)l, 16, 0, 0);
}

// ---------------------------------------------------------------------------
// prep: fused W_qkv/W_proj row-normalize + x bf16 copy + x inv-norm.
// 2048 blocks x 256 threads; each wave handles one 512-float row.
// ---------------------------------------------------------------------------
__global__ __launch_bounds__(256) void prep_kernel(
    const float* __restrict__ W_qkv, const float* __restrict__ W_proj,
    const float* __restrict__ x,
    ushort_t* __restrict__ Wqn, ushort_t* __restrict__ Wpn,
    ushort_t* __restrict__ xb, float* __restrict__ xs) {
  const int row_g = blockIdx.x * 4 + (threadIdx.x >> 6);   // 0..8191
  const int t = threadIdx.x & 63;
  const float* src;
  ushort_t* dst;
  int row;
  bool isx = false;
  if (row_g < 3072)      { src = W_qkv;  dst = Wqn; row = row_g; }
  else if (row_g < 4096) { src = W_proj; dst = Wpn; row = row_g - 3072; }
  else                   { src = x;      dst = xb;  row = row_g - 4096; isx = true; }

  const float4* p = (const float4*)(src + (size_t)row * CDIM);
  float4 a = p[t];
  float4 b = p[t + 64];
  float s = a.x * a.x + a.y * a.y + a.z * a.z + a.w * a.w
          + b.x * b.x + b.y * b.y + b.z * b.z + b.w * b.w;
#pragma unroll
  for (int off = 32; off > 0; off >>= 1) s += __shfl_down(s, off);
  s = __shfl(s, 0);
  float inv;
  if (isx) {
    if (t == 0) xs[row] = 1.0f / (sqrtf(s) * SQRT_C);
    inv = 1.0f;
  } else {
    inv = 1.0f / sqrtf(s);
  }
  short4v ya, yb;
  ya[0] = (short)f2b(a.x * inv); ya[1] = (short)f2b(a.y * inv);
  ya[2] = (short)f2b(a.z * inv); ya[3] = (short)f2b(a.w * inv);
  yb[0] = (short)f2b(b.x * inv); yb[1] = (short)f2b(b.y * inv);
  yb[2] = (short)f2b(b.z * inv); yb[3] = (short)f2b(b.w * inv);
  *(short4v*)&dst[(size_t)row * CDIM + t * 4] = ya;
  *(short4v*)&dst[(size_t)row * CDIM + 256 + t * 4] = yb;
}

// ---------------------------------------------------------------------------
// bcos GEMM, bf16 MFMA 16x16x32. 128m x 64ch tile, BK=64 as two BK=32
// sub-stages. LDS pool (32 KB) staged, then reused by the MODE-0 epilogue
// as a transpose buffer for coalesced Q/K/V stores.
// MODE 0: Qb [bh][n][64] (x0.125), Kt/Vt [bh][d][n]; ascale = x invnorm.
// MODE 1: fp32 out; osum_p[8][4096] summed in LDS, rsqrt in epilogue.
// ---------------------------------------------------------------------------
template <int MODE>
__global__ __launch_bounds__(256) void gemm_mfma_kernel(
    const ushort_t* __restrict__ Ab,
    const ushort_t* __restrict__ Wn,
    const float* __restrict__ ascale,
    const float* __restrict__ osum_p,
    float* __restrict__ out,
    ushort_t* __restrict__ Qb, ushort_t* __restrict__ Ktb,
    ushort_t* __restrict__ Vtb,
    int P) {
  __shared__ __align__(16) ushort_t pool[16384];   // 32 KB
  __shared__ float osl[128];
  const int t = threadIdx.x;
  const int lane = t & 63;
  const int w = t >> 6;
  const int mq = w & 1, wq = w >> 1;
  const int l15 = lane & 15, l4 = lane >> 4;
  const int n0 = blockIdx.x * 64;
  const int mb = blockIdx.y * 128;

  if (MODE == 1) {
    if (t < 128) {
      float s = 0.f;
#pragma unroll
      for (int hh = 0; hh < 8; ++hh) s += osum_p[hh * TOK + mb + t];
      osl[t] = s;
    }
  }

  const int srow = lane >> 2;
  const int sch = (lane & 3) * 8;
  const ushort_t* ag[2];
  const ushort_t* wg[2];
  ushort_t* al[2];
  ushort_t* wl[2];
#pragma unroll
  for (int i = 0; i < 2; ++i) {
    int r = w * 32 + i * 16;
    ag[i] = Ab + (size_t)(mb + r + srow) * CDIM + sch;
    al[i] = pool + r * 32;
    int g = r >> 4;
    int grow = n0 + (g >> 1) * 16 + srow + (g & 1) * P;
    wg[i] = Wn + (size_t)grow * CDIM + sch;
    wl[i] = pool + 8192 + r * 32;
  }

  f32x4 acc[4][4];
#pragma unroll
  for (int i = 0; i < 4; ++i)
#pragma unroll
    for (int j = 0; j < 4; ++j) acc[i][j] = (f32x4){0.f, 0.f, 0.f, 0.f};

  for (int it = 0; it < 8; ++it) {
    __syncthreads();
#pragma unroll
    for (int h = 0; h < 2; ++h)
#pragma unroll
      for (int i = 0; i < 2; ++i) {
        gload16(ag[i] + h * 32, al[i] + h * 4096);
        gload16(wg[i] + h * 32, wl[i] + h * 4096);
      }
#pragma unroll
    for (int i = 0; i < 2; ++i) { ag[i] += 64; wg[i] += 64; }
    __syncthreads();
#pragma unroll
    for (int h = 0; h < 2; ++h) {
      short8 af[4], wf[4];
#pragma unroll
      for (int i = 0; i < 4; ++i)
        af[i] = *(const short8*)(pool + h * 4096 + (mq * 64 + i * 16 + l15) * 32 + l4 * 8);
#pragma unroll
      for (int j = 0; j < 4; ++j)
        wf[j] = *(const short8*)(pool + 8192 + h * 4096 + (wq * 64 + j * 16 + l15) * 32 + l4 * 8);
#pragma unroll
      for (int i = 0; i < 4; ++i)
#pragma unroll
        for (int j = 0; j < 4; ++j)
          acc[i][j] = __builtin_amdgcn_mfma_f32_16x16x32_bf16(af[i], wf[j], acc[i][j], 0, 0, 0);
    }
  }

  if (MODE == 0) {
    const int which = n0 >> 9;
    const int h = (n0 & 511) >> 6;
    const int b = mb >> 11;
    const int bh = b * NHEADS + h;
    const int nsb = mb & 2047;
    __syncthreads();                     // staging pool now free for transpose
    if (which == 0) {
      // Q: LDS [n 128][dh 64] pad 72
#pragma unroll
      for (int i = 0; i < 4; ++i) {
        const int ml = mq * 64 + i * 16 + l4 * 4;
        const float4 asc = *(const float4*)&ascale[mb + ml];
        const float ascv[4] = {asc.x, asc.y, asc.z, asc.w};
#pragma unroll
        for (int jt = 0; jt < 2; ++jt) {
          const int dh = (wq * 2 + jt) * 16 + l15;
          f32x4 a0 = acc[i][2 * jt], a1 = acc[i][2 * jt + 1];
#pragma unroll
          for (int r = 0; r < 4; ++r) {
            float v = fmaxf(a0[r], a1[r]);
            pool[(ml + r) * 72 + dh] = f2b(v * fabsf(v) * ascv[r] * ATTN_SCALE);
          }
        }
      }
      __syncthreads();
      ushort_t* gq = Qb + ((size_t)bh * NSEQ + nsb) * DH;
#pragma unroll
      for (int p = 0; p < 4; ++p) {
        int idx = p * 256 + t;
        int row = idx >> 3, c8 = idx & 7;
        *(short8*)(gq + row * DH + c8 * 8) = *(const short8*)(pool + row * 72 + c8 * 8);
      }
    } else {
      // K/V: LDS [dh 64][n 128] pad 136
#pragma unroll
      for (int i = 0; i < 4; ++i) {
        const int ml = mq * 64 + i * 16 + l4 * 4;
        const float4 asc = *(const float4*)&ascale[mb + ml];
        const float ascv[4] = {asc.x, asc.y, asc.z, asc.w};
#pragma unroll
        for (int jt = 0; jt < 2; ++jt) {
          const int dh = (wq * 2 + jt) * 16 + l15;
          f32x4 a0 = acc[i][2 * jt], a1 = acc[i][2 * jt + 1];
          short4v pv;
#pragma unroll
          for (int r = 0; r < 4; ++r) {
            float v = fmaxf(a0[r], a1[r]);
            pv[r] = (short)f2b(v * fabsf(v) * ascv[r]);
          }
          *(short4v*)(pool + dh * 136 + ml) = pv;
        }
      }
      __syncthreads();
      ushort_t* gk = ((which == 1) ? Ktb : Vtb) + (size_t)bh * DH * NSEQ + nsb;
#pragma unroll
      for (int p = 0; p < 4; ++p) {
        int idx = p * 256 + t;
        int dh_r = idx >> 4, ch = idx & 15;
        *(short8*)(gk + (size_t)dh_r * NSEQ + ch * 8) =
            *(const short8*)(pool + dh_r * 136 + ch * 8);
      }
    }
  } else {
#pragma unroll
    for (int i = 0; i < 4; ++i) {
      const int ml = mq * 64 + i * 16 + l4 * 4;
      const int m = mb + ml;
      float ascv[4];
#pragma unroll
      for (int r = 0; r < 4; ++r) ascv[r] = 1.0f / (sqrtf(osl[ml + r]) * SQRT_C);
#pragma unroll
      for (int jt = 0; jt < 2; ++jt) {
        const int c = n0 + (wq * 2 + jt) * 16 + l15;
        f32x4 a0 = acc[i][2 * jt], a1 = acc[i][2 * jt + 1];
#pragma unroll
        for (int r = 0; r < 4; ++r) {
          float v = fmaxf(a0[r], a1[r]);
          out[(size_t)(m + r) * CDIM + c] = v * fabsf(v) * ascv[r];
        }
      }
    }
  }
}

// ---------------------------------------------------------------------------
// kvstat: grid (8,16) = 128 blocks. Per-slice partials, staged LDS reduce,
// zero atomics. Agp[slice][bh][66*64]: rows 0..63 M^T[dh][d], 64 ksum, 65 vsum.
// ---------------------------------------------------------------------------
__global__ __launch_bounds__(256) void kvstat_kernel(
    const ushort_t* __restrict__ Ktb,
    const ushort_t* __restrict__ Vtb,
    float* __restrict__ Agp) {
  __shared__ float Lr[2 * 66 * 66];
  const int t = threadIdx.x;
  const int lane = t & 63;
  const int w = t >> 6;
  const int l31 = lane & 31;
  const int H = lane >> 5;
  const int bh = blockIdx.y;
  const int n0 = blockIdx.x * 256 + w * 64;

  short8 onesf;
  {
    short v = (l31 == 0) ? (short)0x3F80 : (short)0;
#pragma unroll
    for (int i = 0; i < 8; ++i) onesf[i] = v;
  }

  f32x16 acc[3][3];
#pragma unroll
  for (int mt = 0; mt < 3; ++mt)
#pragma unroll
    for (int nt = 0; nt < 3; ++nt) acc[mt][nt] = fzero16();

  const ushort_t* Kbase = Ktb + (size_t)bh * DH * NSEQ;
  const ushort_t* Vbase = Vtb + (size_t)bh * DH * NSEQ;
#pragma unroll
  for (int c = 0; c < 4; ++c) {
    const int key = n0 + c * 16 + H * 8;
    short8 kf[2], vf[2];
#pragma unroll
    for (int mt = 0; mt < 2; ++mt) {
      kf[mt] = *(const short8*)(Kbase + (size_t)(mt * 32 + l31) * NSEQ + key);
      vf[mt] = *(const short8*)(Vbase + (size_t)(mt * 32 + l31) * NSEQ + key);
    }
#pragma unroll
    for (int mt = 0; mt < 3; ++mt) {
      short8 a = (mt < 2) ? kf[mt] : onesf;
#pragma unroll
      for (int nt = 0; nt < 3; ++nt) {
        if (mt == 2 && nt == 2) continue;
        short8 bfr = (nt < 2) ? vf[nt] : onesf;
        acc[mt][nt] = __builtin_amdgcn_mfma_f32_32x32x16_bf16(a, bfr, acc[mt][nt], 0, 0, 0);
      }
    }
  }

  float* D = Lr + (w & 1) * (66 * 66);
  if (w < 2) {
#pragma unroll
    for (int mt = 0; mt < 3; ++mt)
#pragma unroll
      for (int nt = 0; nt < 3; ++nt) {
        if (mt == 2 && nt == 2) continue;
#pragma unroll
        for (int r = 0; r < 16; ++r) {
          int rloc = (r & 3) + 8 * (r >> 2) + 4 * H;
          int row = (mt < 2) ? mt * 32 + rloc : 64;
          int col = (nt < 2) ? nt * 32 + l31 : 64;
          bool valid = (mt < 2 || rloc == 0) && (nt < 2 || l31 == 0);
          if (valid) D[row * 66 + col] = acc[mt][nt][r];
        }
      }
  }
  __syncthreads();
  if (w >= 2) {
#pragma unroll
    for (int mt = 0; mt < 3; ++mt)
#pragma unroll
      for (int nt = 0; nt < 3; ++nt) {
        if (mt == 2 && nt == 2) continue;
#pragma unroll
        for (int r = 0; r < 16; ++r) {
          int rloc = (r & 3) + 8 * (r >> 2) + 4 * H;
          int row = (mt < 2) ? mt * 32 + rloc : 64;
          int col = (nt < 2) ? nt * 32 + l31 : 64;
          bool valid = (mt < 2 || rloc == 0) && (nt < 2 || l31 == 0);
          if (valid) D[row * 66 + col] += acc[mt][nt][r];
        }
      }
  }
  __syncthreads();

  float* ag = Agp + ((size_t)blockIdx.x * NBH + bh) * (66 * 64);
  const float* L0 = Lr;
  const float* L1 = Lr + 66 * 66;
  for (int e = t; e < 66 * 64; e += 256) {
    int j = e >> 6, i = e & 63;
    int idx = (j < 64) ? i * 66 + j : (j == 64 ? i * 66 + 64 : 64 * 66 + i);
    ag[e] = L0[idx] + L1[idx];
  }
}

// ---------------------------------------------------------------------------
// attn_apply: attn = (vsum + q~.M)/(2048 + q~.ksum); sums 8 partial slices.
// Writes bf16 attn + per-head osum partials (non-atomic).
// ---------------------------------------------------------------------------
__global__ __launch_bounds__(256) void attn_apply_kernel(
    const ushort_t* __restrict__ Qb,
    const float* __restrict__ Agp,
    ushort_t* __restrict__ attnb,
    float* __restrict__ osum_p) {      // [8][4096]
  __shared__ ushort_t Bs[96 * 72];
  __shared__ float vs_lds[64];
  const int t = threadIdx.x;
  const int lane = t & 63;
  const int w = t >> 6;
  const int l31 = lane & 31;
  const int H = lane >> 5;
  const int bh = blockIdx.y;
  const int tok0 = blockIdx.x * 128 + w * 32;

  const float* agp = Agp + (size_t)bh * (66 * 64);
  const size_t sstr = (size_t)NBH * 66 * 64;
  for (int e = t; e < 64 * 64; e += 256) {
    float s = 0.f;
#pragma unroll
    for (int sl = 0; sl < 8; ++sl) s += agp[sl * sstr + e];
    Bs[(e >> 6) * 72 + (e & 63)] = f2b(s);
  }
  for (int e = t; e < 32 * 64; e += 256) {
    int j = e >> 6, i = e & 63;
    ushort_t v = 0;
    if (j == 0) {
      float s = 0.f;
#pragma unroll
      for (int sl = 0; sl < 8; ++sl) s += agp[sl * sstr + 64 * 64 + i];
      v = f2b(s);
    }
    Bs[(64 + j) * 72 + i] = v;
  }
  if (t < 64) {
    float s = 0.f;
#pragma unroll
    for (int sl = 0; sl < 8; ++sl) s += agp[sl * sstr + 65 * 64 + t];
    vs_lds[t] = s;
  }
  __syncthreads();

  short8 qf[4];
  {
    const ushort_t* qp = Qb + ((size_t)bh * NSEQ + tok0 + l31) * DH + H * 8;
#pragma unroll
    for (int c = 0; c < 4; ++c) qf[c] = *(const short8*)(qp + c * 16);
  }

  f32x16 oacc[3];
#pragma unroll
  for (int nt = 0; nt < 3; ++nt) oacc[nt] = fzero16();
#pragma unroll
  for (int c = 0; c < 4; ++c) {
#pragma unroll
    for (int nt = 0; nt < 3; ++nt) {
      short8 bfr = *(const short8*)(Bs + (nt * 32 + l31) * 72 + c * 16 + H * 8);
      oacc[nt] = __builtin_amdgcn_mfma_f32_32x32x16_bf16(qf[c], bfr, oacc[nt], 0, 0, 0);
    }
  }

  const int b = bh >> 3, h = bh & 7;
#pragma unroll
  for (int r = 0; r < 16; ++r) {
    int rloc = (r & 3) + 8 * (r >> 2) + 4 * H;
    float den = 2048.0f + __shfl(oacc[2][r], H * 32);
    float inv = 1.0f / den;
    float v0 = (vs_lds[l31] + oacc[0][r]) * inv;
    float v1 = (vs_lds[32 + l31] + oacc[1][r]) * inv;
    int n = tok0 + rloc;
    ushort_t* op = attnb + ((size_t)(b * NSEQ + n)) * CDIM + h * DH;
    op[l31] = f2b(v0);
    op[32 + l31] = f2b(v1);
    float ss = v0 * v0 + v1 * v1;
#pragma unroll
    for (int off = 16; off > 0; off >>= 1) ss += __shfl_down(ss, off, 32);
    if (l31 == 0) osum_p[h * TOK + b * NSEQ + n] = ss;
  }
}

extern "C" void kernel_launch(void* const* d_in, const int* in_sizes, int n_in,
                              void* d_out, int out_size, void* d_ws, size_t ws_size,
                              hipStream_t stream) {
  const float* x      = (const float*)d_in[0];
  const float* W_qkv  = (const float*)d_in[1];
  const float* W_proj = (const float*)d_in[2];
  float* out = (float*)d_out;

  char* wsb = (char*)d_ws;
  ushort_t* Wqn = (ushort_t*)(wsb + 0);          // 3072x512 bf16
  ushort_t* Wpn = (ushort_t*)(wsb + 3145728);    // 1024x512 bf16
  ushort_t* xb  = (ushort_t*)(wsb + 4194304);    // 4096x512 bf16; reused as attnb
  ushort_t* Qb  = (ushort_t*)(wsb + 8388608);    // [bh][n][64] bf16
  ushort_t* Ktb = (ushort_t*)(wsb + 12582912);   // [bh][d][n] bf16
  ushort_t* Vtb = (ushort_t*)(wsb + 16777216);   // [bh][dh][n] bf16
  float* xs     = (float*)(wsb + 20971520);      // 4096
  float* osum_p = (float*)(wsb + 20987904);      // 8 x 4096
  float* Agp    = (float*)(wsb + 21118976);      // 8 x 16 x 66*64

  prep_kernel<<<2048, 256, 0, stream>>>(W_qkv, W_proj, x, Wqn, Wpn, xb, xs);

  gemm_mfma_kernel<0><<<dim3(24, 32), 256, 0, stream>>>(
      xb, Wqn, xs, nullptr, nullptr, Qb, Ktb, Vtb, 1536);

  kvstat_kernel<<<dim3(8, NBH), 256, 0, stream>>>(Ktb, Vtb, Agp);

  attn_apply_kernel<<<dim3(16, NBH), 256, 0, stream>>>(Qb, Agp, xb, osum_p);

  gemm_mfma_kernel<1><<<dim3(8, 32), 256, 0, stream>>>(
      xb, Wpn, nullptr, osum_p, out, nullptr, nullptr, nullptr, 512);
}